// Round 1
// baseline (534.553 us; speedup 1.0000x reference)
//
#include <hip/hip_runtime.h>

#define GN 1024
#define GNN (GN * GN)
#define GP 16
#define NUM_OUT 127   // ys[1:] = T_1 .. T_127

// Exact fp32 constants:
//   inv_dx2 = 1023^2 = 1046529 (exactly representable)
//   inv_2dx = 1023/2 = 511.5   (exact)
//   DT      = 1e-7f
__device__ __forceinline__ float bilin16(const float* __restrict__ m,
                                         int i0, int i1, float wi,
                                         int j0, int j1, float wj) {
    float m00 = m[i0 * GP + j0];
    float m10 = m[i1 * GP + j0];
    float m01 = m[i0 * GP + j1];
    float m11 = m[i1 * GP + j1];
    float r0 = m00 * (1.0f - wi) + m10 * wi;   // rows term at col j0
    float r1 = m01 * (1.0f - wi) + m11 * wi;   // rows term at col j1
    return r0 * (1.0f - wj) + r1 * wj;
}

__device__ __forceinline__ void coord16(int t, int& c0, int& c1, float& w) {
    // coords = linspace(0, 15, 1024):  c = t * 15/1023
    double c = (double)t * (15.0 / 1023.0);
    c0 = (int)c;                 // floor (c >= 0)
    c1 = c0 + 1 > 15 ? 15 : c0 + 1;
    w  = (float)(c - (double)c0);
}

// Precompute full 1024x1024 resized coefficient maps into workspace.
__global__ __launch_bounds__(256)
void resize_maps_kernel(const float* __restrict__ alpha,
                        const float* __restrict__ kappa,
                        float* __restrict__ Amap,
                        float* __restrict__ Kmap) {
    int idx = blockIdx.x * 256 + threadIdx.x;
    if (idx >= GNN) return;
    int i = idx >> 10;
    int j = idx & (GN - 1);
    int i0, i1, j0, j1; float wi, wj;
    coord16(i, i0, i1, wi);
    coord16(j, j0, j1, wj);
    Amap[idx] = bilin16(alpha, i0, i1, wi, j0, j1, wj);
    Kmap[idx] = bilin16(kappa, i0, i1, wi, j0, j1, wj);
}

// One explicit step. T_new[i,j] = interior(clamp(i,1,N-2), clamp(j,1,N-2))
// (this reproduces the reference's row-then-col boundary replication,
// including corners).
template <bool INLINE_MAPS>
__global__ __launch_bounds__(256)
void step_kernel(const float* __restrict__ Tp,   // previous state (full 1024^2)
                 float* __restrict__ Tn,         // next state (output slab)
                 const float* __restrict__ Aarg, // Amap (full) or alpha (16x16)
                 const float* __restrict__ Karg) // Kmap (full) or kappa (16x16)
{
    int j = blockIdx.x * 256 + threadIdx.x;
    int i = blockIdx.y;

    int ic = i < 1 ? 1 : (i > GN - 2 ? GN - 2 : i);
    int jc = j < 1 ? 1 : (j > GN - 2 ? GN - 2 : j);

    const float* rowc = Tp + ic * GN;
    float Tc  = rowc[jc];
    float Tim = Tp[(ic - 1) * GN + jc];
    float Tip = Tp[(ic + 1) * GN + jc];
    float Tjm = rowc[jc - 1];
    float Tjp = rowc[jc + 1];

    float a, k;
    if (INLINE_MAPS) {
        int i0, i1, j0, j1; float wi, wj;
        coord16(ic, i0, i1, wi);
        coord16(jc, j0, j1, wj);
        a = bilin16(Aarg, i0, i1, wi, j0, j1, wj);
        k = bilin16(Karg, i0, i1, wi, j0, j1, wj);
    } else {
        a = Aarg[ic * GN + jc];
        k = Karg[ic * GN + jc];
    }

    float Txx = (Tim - 2.0f * Tc + Tip) * 1046529.0f;
    float Tyy = (Tjm - 2.0f * Tc + Tjp) * 1046529.0f;
    float Tx  = (Tip - Tim) * 511.5f;
    float Ty  = (Tjp - Tjm) * 511.5f;

    float val = Tc - 1e-7f * k * (Tc * Tx + Tc * Ty)
                   + 1e-7f * a * (Txx + Tyy);

    Tn[i * GN + j] = val;
}

extern "C" void kernel_launch(void* const* d_in, const int* in_sizes, int n_in,
                              void* d_out, int out_size, void* d_ws, size_t ws_size,
                              hipStream_t stream) {
    const float* u0    = (const float*)d_in[0];
    const float* alpha = (const float*)d_in[1];
    const float* kappa = (const float*)d_in[2];
    float* out = (float*)d_out;

    dim3 blk(256, 1, 1);
    dim3 grd(GN / 256, GN, 1);

    bool use_ws = ws_size >= (size_t)2 * GNN * sizeof(float);

    if (use_ws) {
        float* Amap = (float*)d_ws;
        float* Kmap = Amap + GNN;
        resize_maps_kernel<<<(GNN + 255) / 256, 256, 0, stream>>>(alpha, kappa, Amap, Kmap);

        const float* prev = u0;
        for (int s = 1; s <= NUM_OUT; ++s) {
            float* nxt = out + (size_t)(s - 1) * GNN;
            step_kernel<false><<<grd, blk, 0, stream>>>(prev, nxt, Amap, Kmap);
            prev = nxt;
        }
    } else {
        const float* prev = u0;
        for (int s = 1; s <= NUM_OUT; ++s) {
            float* nxt = out + (size_t)(s - 1) * GNN;
            step_kernel<true><<<grd, blk, 0, stream>>>(prev, nxt, alpha, kappa);
            prev = nxt;
        }
    }
}

// Round 2
// 436.065 us; speedup vs baseline: 1.2259x; 1.2259x over previous
//
#include <hip/hip_runtime.h>

#define GN   1024
#define GNN  (GN * GN)
#define GP   16
#define NOUT 127          // ys[1:] = T_1 .. T_127
#define TILE 64           // output tile per block
#define KST  8            // fused time steps per launch
#define SZ   (TILE + 2 * KST)   // 80
#define CELLS (SZ * SZ)         // 6400
#define NTHR 1024
#define NC   7            // ceil(CELLS / NTHR)

// Exact fp32 constants: inv_dx2 = 1023^2 = 1046529, inv_2dx = 511.5, DT = 1e-7f

__device__ __forceinline__ void coord16(int t, int& c0, int& c1, float& w) {
    // coords = linspace(0, 15, 1024): c = t * 15/1023
    double c = (double)t * (15.0 / 1023.0);
    c0 = (int)c;
    c1 = c0 + 1 > 15 ? 15 : c0 + 1;
    w  = (float)(c - (double)c0);
}

__device__ __forceinline__ float bilin16(const float* __restrict__ m,
                                         int i0, int i1, float wi,
                                         int j0, int j1, float wj) {
    float m00 = m[i0 * GP + j0];
    float m10 = m[i1 * GP + j0];
    float m01 = m[i0 * GP + j1];
    float m11 = m[i1 * GP + j1];
    float r0 = m00 * (1.0f - wi) + m10 * wi;
    float r1 = m01 * (1.0f - wi) + m11 * wi;
    return r0 * (1.0f - wj) + r1 * wj;
}

// Temporal-blocked stepper: computes states base+1 .. base+kk from state `base`
// (in src), writing each state's core 64x64 tile into its d_out slab.
// T_new[i,j] = interior(clamp(i,1,N-2), clamp(j,1,N-2)) reproduces the
// reference's row-then-col boundary replication exactly.
__global__ __launch_bounds__(NTHR)
void fused_steps_kernel(const float* __restrict__ src,
                        const float* __restrict__ alpha,
                        const float* __restrict__ kappa,
                        float* __restrict__ out,
                        int base, int kk)
{
    __shared__ float buf[2][CELLS];   // 2 x 25.6 KB double buffer

    const int tid = threadIdx.x;
    const int gi0 = blockIdx.y * TILE;
    const int gj0 = blockIdx.x * TILE;

    // Valid-window parameters. Window at step t: [lo_s + shl*t, hi_s - shh*t].
    // Physical-boundary sides don't shrink (clamped stencil keeps reads inside).
    const int lo_i_s = (gi0 == 0)         ? KST            : 0;
    const int shl_i  = (gi0 == 0)         ? 0              : 1;
    const int hi_i_s = (gi0 + TILE == GN) ? (KST + TILE-1) : (SZ - 1);
    const int shh_i  = (gi0 + TILE == GN) ? 0              : 1;
    const int lo_j_s = (gj0 == 0)         ? KST            : 0;
    const int shl_j  = (gj0 == 0)         ? 0              : 1;
    const int hi_j_s = (gj0 + TILE == GN) ? (KST + TILE-1) : (SZ - 1);
    const int shh_j  = (gj0 + TILE == GN) ? 0              : 1;

    // Per-cell static data (fully unrolled -> registers, rule #20)
    int   cli[NC], clj[NC], coff[NC], woff[NC], goff[NC];
    float av[NC], kv[NC];
    bool  core[NC];

    #pragma unroll
    for (int m = 0; m < NC; ++m) {
        int c = tid + m * NTHR;
        if (c < CELLS) {
            int li = c / SZ, lj = c % SZ;
            int gi = gi0 - KST + li, gj = gj0 - KST + lj;
            int ci = gi < 1 ? 1 : (gi > GN - 2 ? GN - 2 : gi);
            int cj = gj < 1 ? 1 : (gj > GN - 2 ? GN - 2 : gj);
            cli[m]  = li;
            clj[m]  = lj;
            coff[m] = (ci - (gi0 - KST)) * SZ + (cj - (gj0 - KST)); // clamped center, local
            woff[m] = c;                                            // li*SZ + lj
            goff[m] = gi * GN + gj;
            core[m] = (li >= KST && li < KST + TILE && lj >= KST && lj < KST + TILE);
            int i0, i1, j0, j1; float wi, wj;
            coord16(ci, i0, i1, wi);
            coord16(cj, j0, j1, wj);
            av[m] = bilin16(alpha, i0, i1, wi, j0, j1, wj);
            kv[m] = bilin16(kappa, i0, i1, wi, j0, j1, wj);
        } else {
            cli[m] = -1000; clj[m] = -1000;       // never inside any window
            coff[m] = 0; woff[m] = 0; goff[m] = 0;
            core[m] = false; av[m] = 0.0f; kv[m] = 0.0f;
        }
    }

    // Initial load: in-grid cells of the 80x80 halo region (window at t=0)
    #pragma unroll
    for (int m = 0; m < NC; ++m) {
        int li = cli[m], lj = clj[m];
        if (li >= lo_i_s && li <= hi_i_s && lj >= lo_j_s && lj <= hi_j_s)
            buf[0][woff[m]] = src[goff[m]];
    }
    __syncthreads();

    int p = 0;
    for (int t = 1; t <= kk; ++t) {
        float* __restrict__ slab = out + (size_t)(base + t - 1) * GNN;
        const float* __restrict__ cur = buf[p];
        float* __restrict__ nxt = buf[p ^ 1];
        const int loi = lo_i_s + shl_i * t, hii = hi_i_s - shh_i * t;
        const int loj = lo_j_s + shl_j * t, hij = hi_j_s - shh_j * t;

        #pragma unroll
        for (int m = 0; m < NC; ++m) {
            if (cli[m] >= loi && cli[m] <= hii && clj[m] >= loj && clj[m] <= hij) {
                const int co = coff[m];
                float Tc  = cur[co];
                float Tim = cur[co - SZ];
                float Tip = cur[co + SZ];
                float Tjm = cur[co - 1];
                float Tjp = cur[co + 1];
                float Txx = (Tim - 2.0f * Tc + Tip) * 1046529.0f;
                float Tyy = (Tjm - 2.0f * Tc + Tjp) * 1046529.0f;
                float Tx  = (Tip - Tim) * 511.5f;
                float Ty  = (Tjp - Tjm) * 511.5f;
                float val = Tc - 1e-7f * kv[m] * (Tc * Tx + Tc * Ty)
                               + 1e-7f * av[m] * (Txx + Tyy);
                nxt[woff[m]] = val;
                if (core[m]) slab[goff[m]] = val;
            }
        }
        __syncthreads();
        p ^= 1;
    }
}

extern "C" void kernel_launch(void* const* d_in, const int* in_sizes, int n_in,
                              void* d_out, int out_size, void* d_ws, size_t ws_size,
                              hipStream_t stream) {
    const float* u0    = (const float*)d_in[0];
    const float* alpha = (const float*)d_in[1];
    const float* kappa = (const float*)d_in[2];
    float* out = (float*)d_out;

    dim3 grd(GN / TILE, GN / TILE, 1);   // 16x16 = 256 blocks = 1/CU

    for (int b = 0; b < NOUT; b += KST) {
        int kk = NOUT - b; if (kk > KST) kk = KST;
        const float* src = (b == 0) ? u0 : out + (size_t)(b - 1) * GNN;
        fused_steps_kernel<<<grd, NTHR, 0, stream>>>(src, alpha, kappa, out, b, kk);
    }
}

// Round 4
// 226.294 us; speedup vs baseline: 2.3622x; 1.9270x over previous
//
#include <hip/hip_runtime.h>

#define GN   1024
#define GNN  (GN * GN)
#define GP   16
#define NOUT 127          // ys[1:] = T_1 .. T_127
#define TILE 64           // output tile per block
#define KST  8            // fused time steps per launch
#define SZ   80           // TILE + 2*KST (region side)
#define NRS  20           // strips per row = SZ/4
#define NSTR 1600         // SZ * NRS
#define NTHR 1024
#define NM   2            // strip passes per thread

// Exact fp32 constants: DT/dx^2 = 1e-7*1023^2 = 0.1046529, DT/(2dx) = 5.115e-5

__device__ __forceinline__ void coord16(int t, int& c0, int& c1, float& w) {
    // coords = linspace(0, 15, 1024): c = t * 15/1023
    double c = (double)t * (15.0 / 1023.0);
    c0 = (int)c;
    c1 = c0 + 1 > 15 ? 15 : c0 + 1;
    w  = (float)(c - (double)c0);
}

__device__ __forceinline__ float bilin16(const float* __restrict__ m,
                                         int i0, int i1, float wi,
                                         int j0, int j1, float wj) {
    float m00 = m[i0 * GP + j0];
    float m10 = m[i1 * GP + j0];
    float m01 = m[i0 * GP + j1];
    float m11 = m[i1 * GP + j1];
    float r0 = m00 * (1.0f - wi) + m10 * wi;
    float r1 = m01 * (1.0f - wi) + m11 * wi;
    return r0 * (1.0f - wj) + r1 * wj;
}

__device__ __forceinline__ float cellv(float C, float L, float R, float U, float D,
                                       float a2, float k2) {
    // val = C - k2*C*((D-U)+(R-L)) + a2*(U+D+L+R-4C)
    float s   = (D - U) + (R - L);
    float lap = fmaf(-4.0f, C, (U + D) + (L + R));
    return fmaf(a2, lap, fmaf(-k2, C * s, C));
}

// Temporal-blocked stepper, stale-halo scheme: computes ALL SZ x SZ region
// cells every step with locally-clamped stencil (no window checks).
// Register carry V[m] holds the CLAMPED row's values (critical: at physical
// top/bottom rows the stencil center is the adjacent interior row, which
// lives in another thread's registers — carrying the clamped row makes the
// boundary strip's computation operand-identical to its interior neighbor,
// i.e. exact boundary replication by induction). Interior region edges are
// stale-tolerated: contamination advances <=1 cell/step, core sits behind an
// 8-deep halo, 8 steps per launch.
__global__ __launch_bounds__(NTHR)
void fused_steps_kernel(const float* __restrict__ src,
                        const float* __restrict__ alpha,
                        const float* __restrict__ kappa,
                        float* __restrict__ out,
                        int base, int kk)
{
    __shared__ float buf[2][SZ * SZ];   // 2 x 25.6 KB

    const int tid = threadIdx.x;
    const int gi0 = blockIdx.y * TILE;
    const int gj0 = blockIdx.x * TILE;
    int oi = gi0 - KST; oi = oi < 0 ? 0 : (oi > GN - SZ ? GN - SZ : oi);
    int oj = gj0 - KST; oj = oj < 0 ? 0 : (oj > GN - SZ ? GN - SZ : oj);
    const int di = gi0 - oi;            // core row offset in region (0, 8, or 16)
    const int dj = gj0 - oj;

    bool  act[NM], isl[NM], isr[NM], core[NM];
    int   voff[NM], upoff[NM], dnoff[NM], sloff[NM], sroff[NM], goff[NM], cgoff[NM];
    float a2[NM][4], k2[NM][4];
    float4 V[NM];

    #pragma unroll
    for (int m = 0; m < NM; ++m) {
        int s = tid + m * NTHR;
        act[m] = (s < NSTR);
        int ss = act[m] ? s : 0;
        int r = ss / NRS, c = ss % NRS;
        int gi = oi + r;
        int cig = gi < 1 ? 1 : (gi > GN - 2 ? GN - 2 : gi);
        int ai = cig - oi; ai = ai < 1 ? 1 : (ai > SZ - 2 ? SZ - 2 : ai);
        isl[m] = (c == 0);
        isr[m] = (c == NRS - 1);
        voff[m]  = r * SZ + 4 * c;
        upoff[m] = (ai - 1) * SZ + 4 * c;
        dnoff[m] = (ai + 1) * SZ + 4 * c;
        sloff[m] = ai * SZ + (isl[m] ? 0      : 4 * c - 1);
        sroff[m] = ai * SZ + (isr[m] ? SZ - 1 : 4 * c + 4);
        goff[m]  = gi  * GN + oj + 4 * c;
        cgoff[m] = cig * GN + oj + 4 * c;   // clamped-row source for register carry
        core[m]  = act[m] && r >= di && r < di + TILE
                          && c >= (dj >> 2) && c < (dj >> 2) + 16;
        int i0, i1; float wi;
        coord16(cig, i0, i1, wi);
        #pragma unroll
        for (int u = 0; u < 4; ++u) {
            int gj = oj + 4 * c + u;
            int cjg = gj < 1 ? 1 : (gj > GN - 2 ? GN - 2 : gj);
            int j0, j1; float wj;
            coord16(cjg, j0, j1, wj);
            a2[m][u] = bilin16(alpha, i0, i1, wi, j0, j1, wj) * 0.1046529f;
            k2[m][u] = bilin16(kappa, i0, i1, wi, j0, j1, wj) * 5.115e-5f;
        }
    }

    // Initial load: LDS gets the strip's own row; V gets the CLAMPED row.
    #pragma unroll
    for (int m = 0; m < NM; ++m) {
        if (act[m]) {
            float4 ld = *(const float4*)(src + goff[m]);
            *(float4*)&buf[0][voff[m]] = ld;
            V[m] = (cgoff[m] == goff[m]) ? ld
                                         : *(const float4*)(src + cgoff[m]);
        }
    }
    __syncthreads();

    int p = 0;
    for (int t = 1; t <= kk; ++t) {
        const float* __restrict__ cur = buf[p];
        float* __restrict__ nxt = buf[p ^ 1];
        float* __restrict__ slab = out + (long)(base + t - 1) * GNN;

        #pragma unroll
        for (int m = 0; m < NM; ++m) {
            if (act[m]) {
                float4 U = *(const float4*)(cur + upoff[m]);
                float4 D = *(const float4*)(cur + dnoff[m]);
                float sl = cur[sloff[m]];
                float sr = cur[sroff[m]];
                float v0 = V[m].x, v1 = V[m].y, v2 = V[m].z, v3 = V[m].w;

                // Edge-cell operand selection (boundary-replicated clamped centers)
                float L0 = isl[m] ? v0  : sl;
                float C0 = isl[m] ? v1  : v0;
                float R0 = isl[m] ? v2  : v1;
                float U0 = isl[m] ? U.y : U.x;
                float D0 = isl[m] ? D.y : D.x;
                float L3 = isr[m] ? v1  : v2;
                float C3 = isr[m] ? v2  : v3;
                float R3 = isr[m] ? v3  : sr;
                float U3 = isr[m] ? U.z : U.w;
                float D3 = isr[m] ? D.z : D.w;

                float4 NV;
                NV.x = cellv(C0, L0, R0, U0, D0, a2[m][0], k2[m][0]);
                NV.y = cellv(v1, v0, v2, U.y, D.y, a2[m][1], k2[m][1]);
                NV.z = cellv(v2, v1, v3, U.z, D.z, a2[m][2], k2[m][2]);
                NV.w = cellv(C3, L3, R3, U3, D3, a2[m][3], k2[m][3]);

                *(float4*)(nxt + voff[m]) = NV;
                if (core[m]) *(float4*)(slab + goff[m]) = NV;
                V[m] = NV;
            }
        }
        __syncthreads();
        p ^= 1;
    }
}

extern "C" void kernel_launch(void* const* d_in, const int* in_sizes, int n_in,
                              void* d_out, int out_size, void* d_ws, size_t ws_size,
                              hipStream_t stream) {
    const float* u0    = (const float*)d_in[0];
    const float* alpha = (const float*)d_in[1];
    const float* kappa = (const float*)d_in[2];
    float* out = (float*)d_out;

    dim3 grd(GN / TILE, GN / TILE, 1);   // 16x16 = 256 blocks = 1/CU

    for (int b = 0; b < NOUT; b += KST) {
        int kk = NOUT - b; if (kk > KST) kk = KST;
        const float* src = (b == 0) ? u0 : out + (long)(b - 1) * GNN;
        fused_steps_kernel<<<grd, NTHR, 0, stream>>>(src, alpha, kappa, out, b, kk);
    }
}